// Round 9
// baseline (610.229 us; speedup 1.0000x reference)
//
#include <hip/hip_runtime.h>

#define TSTEPS 1024

typedef _Float16 half8 __attribute__((ext_vector_type(8)));
typedef _Float16 half2v __attribute__((ext_vector_type(2)));
typedef float    f32x4 __attribute__((ext_vector_type(4)));

#define MFMA16(A_, B_, C_) __builtin_amdgcn_mfma_f32_16x16x32_f16((A_), (B_), (C_), 0, 0, 0)

__device__ __forceinline__ float fast_rcp(float x) { return __builtin_amdgcn_rcpf(x); }

// reinterpret one float (2 packed halfs) as half2
__device__ __forceinline__ half2v f2h2(float f) {
    union { float f; half2v h; } u; u.f = f; return u.h;
}

// load 8 consecutive fp32 and convert to a packed f16 MFMA fragment (4 VGPRs)
__device__ __forceinline__ half8 load_w8(const float* p) {
    const float4 a = ((const float4*)p)[0];
    const float4 b = ((const float4*)p)[1];
    half8 r;
    r[0] = (_Float16)a.x; r[1] = (_Float16)a.y; r[2] = (_Float16)a.z; r[3] = (_Float16)a.w;
    r[4] = (_Float16)b.x; r[5] = (_Float16)b.y; r[6] = (_Float16)b.z; r[7] = (_Float16)b.w;
    return r;
}

// 2-layer GRU, MFMA + redistributed transcendentals.
// 128 blocks x 8 chains, 8 waves. Per tick:
//  P1: waves 0-3 GRU1 unit-group MFMAs (6 ea), waves 4-5 GRU2 group MFMAs
//      (9 ea, one step behind). Pre-activations (bias in C) -> LDS f32.
//  barrier
//  P2: trans math balanced over ALL 512 lanes:
//      waves 0-3: lane L=wid*64+lane: unit u=L>>2, chains ca=2*(L&3), ca+1
//                 (2 GRU1 triples; persistent fp32 h1 pair in regs)
//      waves 4-7: lane L2=(wid-4)*64+lane: u2=L2>>3, c=L2&7 (1 GRU2 triple)
//      h published f16 to s_h1/s_h2 double buffers (layout [chain][unit] so
//      P1 B-frag reads stay ds_read_b128).
//  barrier
// Sigmoid pair shares one rcp (exact): r=d2*inv, z=d1*inv, inv=rcp(d1*d2);
// args clamped +-17 (sigmoid) / +-9 (tanh) so products can't overflow.
// MFMA layouts (m89/m120-verified): A[m=lane&15][k=quad*8+j],
// B[k=quad*8+j][n=lane&15], C/D: col(n)=lane&15, row(m)=quad*4+reg.
__global__ __launch_bounds__(512, 1)
void gru2_encoder(const float* __restrict__ x,
                  const float* __restrict__ W_ih1,
                  const float* __restrict__ W_hh1,
                  const float* __restrict__ b_ih1,
                  const float* __restrict__ b_hh1,
                  const float* __restrict__ W_ih2,
                  const float* __restrict__ W_hh2,
                  const float* __restrict__ b_ih2,
                  const float* __restrict__ b_hh2,
                  float* __restrict__ out)
{
    const int blk  = blockIdx.x;    // 128 blocks, 8 chains each
    const int tid  = threadIdx.x;   // 512
    const int lane = tid & 63;
    const int wid  = tid >> 6;      // 0..7
    const int nl   = lane & 15;     // MFMA chain-slot (8 real + 8 dead)
    const int quad = lane >> 4;     // 0..3
    const int chain0 = blk * 8;

    __shared__ __align__(16) _Float16 s_h1[2][16][72];   // [par][chain][unit64+pad]
    __shared__ __align__(16) _Float16 s_h2[2][16][40];   // [par][chain][unit32+pad]
    __shared__ __align__(16) _Float16 s_x[TSTEPS][8];    // x f16, [t][chain]
    __shared__ __align__(16) float pre1[3][8][68];       // r,z,hn preacts [chain][unit+pad]
    __shared__ __align__(16) float pre2[4][8][36];       // r,z,nx,nh      [chain][unit+pad]

    // ---- one-time staging
    for (int idx = tid; idx < 8 * TSTEPS; idx += 512) {
        const int c = idx >> 10, t = idx & (TSTEPS - 1);
        s_x[t][c] = (_Float16)x[(size_t)(chain0 + c) * TSTEPS + t];
    }
    {
        _Float16* p1 = &s_h1[0][0][0];
        for (int idx = tid; idx < 2 * 16 * 72; idx += 512) p1[idx] = (_Float16)0.0f;
        _Float16* p2 = &s_h2[0][0][0];
        for (int idx = tid; idx < 2 * 16 * 40; idx += 512) p2[idx] = (_Float16)0.0f;
    }
    __syncthreads();

    // =========== P1 owner setup ===========
    // GRU1 owners (wid 0..3): unit-group U0 = wid*16
    half8 aW0[3], aW1[3];          // [gate r,z,n] x K-chunk
    f32x4 C1[3];                   // C-bias per gate (r:bi+bh, z:bi+bh, n:bh only)
    // GRU2 owners (wid 4..5): unit-group V0 = (wid-4)*16
    half8 A2i0[3], A2i1[3], A2h[3];
    f32x4 C2[4];                   // r, z, nx(bi), nh(bh)
    if (wid < 4) {
        const int U0 = wid * 16;
        const int ur = U0 + nl;
        const int u4 = U0 + quad * 4;
        aW0[0] = load_w8(W_hh1 + (size_t)(ur)       * 64 + quad * 8);
        aW1[0] = load_w8(W_hh1 + (size_t)(ur)       * 64 + 32 + quad * 8);
        aW0[1] = load_w8(W_hh1 + (size_t)(64 + ur)  * 64 + quad * 8);
        aW1[1] = load_w8(W_hh1 + (size_t)(64 + ur)  * 64 + 32 + quad * 8);
        aW0[2] = load_w8(W_hh1 + (size_t)(128 + ur) * 64 + quad * 8);
        aW1[2] = load_w8(W_hh1 + (size_t)(128 + ur) * 64 + 32 + quad * 8);
        const float4 bir = *(const float4*)(b_ih1 + u4);
        const float4 bhr = *(const float4*)(b_hh1 + u4);
        const float4 biz = *(const float4*)(b_ih1 + 64 + u4);
        const float4 bhz = *(const float4*)(b_hh1 + 64 + u4);
        const float4 bhn = *(const float4*)(b_hh1 + 128 + u4);
        C1[0] = f32x4{bir.x + bhr.x, bir.y + bhr.y, bir.z + bhr.z, bir.w + bhr.w};
        C1[1] = f32x4{biz.x + bhz.x, biz.y + bhz.y, biz.z + bhz.z, biz.w + bhz.w};
        C1[2] = f32x4{bhn.x, bhn.y, bhn.z, bhn.w};
    } else if (wid < 6) {
        const int V0 = (wid - 4) * 16;
        const int vr = V0 + nl;
        const int v4 = V0 + quad * 4;
        A2i0[0] = load_w8(W_ih2 + (size_t)(vr)      * 64 + quad * 8);
        A2i1[0] = load_w8(W_ih2 + (size_t)(vr)      * 64 + 32 + quad * 8);
        A2i0[1] = load_w8(W_ih2 + (size_t)(32 + vr) * 64 + quad * 8);
        A2i1[1] = load_w8(W_ih2 + (size_t)(32 + vr) * 64 + 32 + quad * 8);
        A2i0[2] = load_w8(W_ih2 + (size_t)(64 + vr) * 64 + quad * 8);
        A2i1[2] = load_w8(W_ih2 + (size_t)(64 + vr) * 64 + 32 + quad * 8);
        A2h[0]  = load_w8(W_hh2 + (size_t)(vr)      * 32 + quad * 8);
        A2h[1]  = load_w8(W_hh2 + (size_t)(32 + vr) * 32 + quad * 8);
        A2h[2]  = load_w8(W_hh2 + (size_t)(64 + vr) * 32 + quad * 8);
        const float4 bir = *(const float4*)(b_ih2 + v4);
        const float4 bhr = *(const float4*)(b_hh2 + v4);
        const float4 biz = *(const float4*)(b_ih2 + 32 + v4);
        const float4 bhz = *(const float4*)(b_hh2 + 32 + v4);
        const float4 bin = *(const float4*)(b_ih2 + 64 + v4);
        const float4 bhn = *(const float4*)(b_hh2 + 64 + v4);
        C2[0] = f32x4{bir.x + bhr.x, bir.y + bhr.y, bir.z + bhr.z, bir.w + bhr.w};
        C2[1] = f32x4{biz.x + bhz.x, biz.y + bhz.y, biz.z + bhz.z, biz.w + bhz.w};
        C2[2] = f32x4{bin.x, bin.y, bin.z, bin.w};
        C2[3] = f32x4{bhn.x, bhn.y, bhn.z, bhn.w};
    }

    // =========== P2 trans setup ===========
    // GRU1 trans (wid 0..3): unit tu, chains ca, ca+1
    const int L1 = wid * 64 + lane;          // 0..255
    const int tu = L1 >> 2;                  // 0..63
    const int ca = (L1 & 3) * 2;             // 0,2,4,6
    float wxr = 0.f, wxz = 0.f, wxn = 0.f, bNx = 0.f;
    if (wid < 4) {
        wxr = W_ih1[tu]; wxz = W_ih1[64 + tu]; wxn = W_ih1[128 + tu];
        bNx = b_ih1[128 + tu];
    }
    float h1a = 0.0f, h1b = 0.0f;
    // GRU2 trans (wid 4..7): unit u2, chain c2
    const int L2 = (wid - 4) * 64 + lane;    // 0..255 (garbage for wid<4, unused)
    const int u2 = (L2 >> 3) & 31;
    const int c2 = L2 & 7;
    float h2v = 0.0f;

    for (int t = 0; t <= TSTEPS; ++t) {
        // ---------------- P1: MFMA -> preacts ----------------
        if (wid < 4) {
            if (t < TSTEPS) {
                const int pr = (t + 1) & 1;            // h1(t-1)
                const half8 B0 = *(const half8*)&s_h1[pr][nl][quad * 8];
                const half8 B1 = *(const half8*)&s_h1[pr][nl][32 + quad * 8];
                f32x4 aR = MFMA16(aW0[0], B0, C1[0]); aR = MFMA16(aW1[0], B1, aR);
                f32x4 aZ = MFMA16(aW0[1], B0, C1[1]); aZ = MFMA16(aW1[1], B1, aZ);
                f32x4 aN = MFMA16(aW0[2], B0, C1[2]); aN = MFMA16(aW1[2], B1, aN);
                if (nl < 8) {
                    const int U0 = wid * 16;
                    *(f32x4*)&pre1[0][nl][U0 + quad * 4] = aR;
                    *(f32x4*)&pre1[1][nl][U0 + quad * 4] = aZ;
                    *(f32x4*)&pre1[2][nl][U0 + quad * 4] = aN;
                }
            }
        } else if (wid < 6) {
            if (t >= 1) {
                const int pr = (t + 1) & 1;            // h1(t-1)
                const half8 B0 = *(const half8*)&s_h1[pr][nl][quad * 8];
                const half8 B1 = *(const half8*)&s_h1[pr][nl][32 + quad * 8];
                const half8 Bh = *(const half8*)&s_h2[t & 1][nl][quad * 8];   // h2(t-2)
                f32x4 aR = MFMA16(A2i0[0], B0, C2[0]); aR = MFMA16(A2i1[0], B1, aR);
                aR = MFMA16(A2h[0], Bh, aR);
                f32x4 aZ = MFMA16(A2i0[1], B0, C2[1]); aZ = MFMA16(A2i1[1], B1, aZ);
                aZ = MFMA16(A2h[1], Bh, aZ);
                f32x4 aNx = MFMA16(A2i0[2], B0, C2[2]); aNx = MFMA16(A2i1[2], B1, aNx);
                f32x4 aNh = MFMA16(A2h[2], Bh, C2[3]);
                if (nl < 8) {
                    const int V0 = (wid - 4) * 16;
                    *(f32x4*)&pre2[0][nl][V0 + quad * 4] = aR;
                    *(f32x4*)&pre2[1][nl][V0 + quad * 4] = aZ;
                    *(f32x4*)&pre2[2][nl][V0 + quad * 4] = aNx;
                    *(f32x4*)&pre2[3][nl][V0 + quad * 4] = aNh;
                }
            }
        }
        __syncthreads();

        // ---------------- P2: balanced trans math ----------------
        if (wid < 4) {
            if (t < TSTEPS) {
                const float pRa = pre1[0][ca][tu],     pRb = pre1[0][ca + 1][tu];
                const float pZa = pre1[1][ca][tu],     pZb = pre1[1][ca + 1][tu];
                const float pNa = pre1[2][ca][tu],     pNb = pre1[2][ca + 1][tu];
                const half2v xp = f2h2(*(const float*)&s_x[t][ca]);
                const float xa = (float)xp[0], xb = (float)xp[1];
                // chain ca
                {
                    float aR = fminf(fmaxf(fmaf(wxr, xa, pRa), -17.f), 17.f);
                    float aZ = fminf(fmaxf(fmaf(wxz, xa, pZa), -17.f), 17.f);
                    const float ea = __expf(-aR), eb = __expf(-aZ);
                    const float d1 = 1.f + ea, d2 = 1.f + eb;
                    const float inv = fast_rcp(d1 * d2);
                    const float r = d2 * inv, z = d1 * inv;
                    float an = fmaf(wxn, xa, bNx) + r * pNa;
                    an = fminf(fmaxf(an, -9.f), 9.f);
                    const float ec = __expf(2.f * an);
                    const float nn = 1.f - 2.f * fast_rcp(ec + 1.f);
                    h1a = nn + z * (h1a - nn);
                }
                // chain ca+1
                {
                    float aR = fminf(fmaxf(fmaf(wxr, xb, pRb), -17.f), 17.f);
                    float aZ = fminf(fmaxf(fmaf(wxz, xb, pZb), -17.f), 17.f);
                    const float ea = __expf(-aR), eb = __expf(-aZ);
                    const float d1 = 1.f + ea, d2 = 1.f + eb;
                    const float inv = fast_rcp(d1 * d2);
                    const float r = d2 * inv, z = d1 * inv;
                    float an = fmaf(wxn, xb, bNx) + r * pNb;
                    an = fminf(fmaxf(an, -9.f), 9.f);
                    const float ec = __expf(2.f * an);
                    const float nn = 1.f - 2.f * fast_rcp(ec + 1.f);
                    h1b = nn + z * (h1b - nn);
                }
                s_h1[t & 1][ca][tu]     = (_Float16)h1a;
                s_h1[t & 1][ca + 1][tu] = (_Float16)h1b;
            }
        } else {
            if (t >= 1) {
                float aR = fminf(fmaxf(pre2[0][c2][u2], -17.f), 17.f);
                float aZ = fminf(fmaxf(pre2[1][c2][u2], -17.f), 17.f);
                const float pNx = pre2[2][c2][u2];
                const float pNh = pre2[3][c2][u2];
                const float ea = __expf(-aR), eb = __expf(-aZ);
                const float d1 = 1.f + ea, d2 = 1.f + eb;
                const float inv = fast_rcp(d1 * d2);
                const float r2 = d2 * inv, z2 = d1 * inv;
                float an = pNx + r2 * pNh;
                an = fminf(fmaxf(an, -9.f), 9.f);
                const float ec = __expf(2.f * an);
                const float n2 = 1.f - 2.f * fast_rcp(ec + 1.f);
                h2v = n2 + z2 * (h2v - n2);
                s_h2[(t + 1) & 1][c2][u2] = (_Float16)h2v;   // h2(t-1)
            }
        }
        __syncthreads();
    }

    if (wid >= 4) out[(size_t)(chain0 + c2) * 32 + u2] = h2v;
}

extern "C" void kernel_launch(void* const* d_in, const int* in_sizes, int n_in,
                              void* d_out, int out_size, void* d_ws, size_t ws_size,
                              hipStream_t stream) {
    const float* x     = (const float*)d_in[0];
    const float* W_ih1 = (const float*)d_in[1];
    const float* W_hh1 = (const float*)d_in[2];
    const float* b_ih1 = (const float*)d_in[3];
    const float* b_hh1 = (const float*)d_in[4];
    const float* W_ih2 = (const float*)d_in[5];
    const float* W_hh2 = (const float*)d_in[6];
    const float* b_ih2 = (const float*)d_in[7];
    const float* b_hh2 = (const float*)d_in[8];
    float* out = (float*)d_out;

    gru2_encoder<<<dim3(128), dim3(512), 0, stream>>>(
        x, W_ih1, W_hh1, b_ih1, b_hh1, W_ih2, W_hh2, b_ih2, b_hh2, out);
}